// Round 2
// baseline (175.213 us; speedup 1.0000x reference)
//
#include <hip/hip_runtime.h>
#include <hip/hip_bf16.h>

// NonlocalBlock: B=4, C=64, H=W=96 (N=9216), Ci=32, COMPRESSION=2 (M=4608).
// R7: occupancy push. R6 post-mortem showed util flat under re-scheduling and
//     perf tracking occupancy -> latency/residency-bound. Changes vs R5:
//     (a) m-subtile 64->32: P LDS 8KB->4KB/wave (8KB/block, 20-block LDS cap),
//         kf/vf register buffers halved;
//     (b) lsum via per-lane scalar adds on the exp values (+shfl_xor butterfly
//         at the end) instead of ones-row MFMA: -16 AGPR, -4 VGPR, -20% MFMAs;
//     (c) ks 8->12 (grid 3456 = 13.5 blocks/CU) to fill the freed residency;
//     (d) __launch_bounds__(128,5) to cap regs at 102 (hand tally ~85).
//     No interleave, no setprio (R6 regression). proj/reduce unchanged.

#define NQ 9216
#define MM 4608
#define KS 12          // split-K factor (m splits)
#define TPW 12         // 32-m tiles per wave: KS*TPW*32 == MM
#define LOG2E 1.44269504088896340736f

typedef __attribute__((ext_vector_type(8))) short bf16x8;   // 8 bf16, 4 VGPRs
typedef __attribute__((ext_vector_type(4))) float f32x4;    // MFMA C/D
typedef __attribute__((ext_vector_type(4))) unsigned short u16x4;

static __device__ __forceinline__ unsigned pk2(float a, float b) {
    __hip_bfloat162 h = __float22bfloat162_rn(make_float2(a, b));
    return *reinterpret_cast<unsigned*>(&h);   // low16=a, high16=b
}

// ---------------------------------------------------------------------------
// Kernel 1: projections + zero-fill of partial buffers. 1152 blocks x 128 thr
// (2 waves, 1 n-tile of 16 each). theta pre-scaled by LOG2E; phi [m][ci];
// gT [ci][m] via LDS transpose.
// ---------------------------------------------------------------------------
__global__ __launch_bounds__(128, 4) void proj_kernel(
    const float* __restrict__ x,
    const float* __restrict__ wt, const float* __restrict__ bt,
    const float* __restrict__ wp, const float* __restrict__ bp,
    const float* __restrict__ wg, const float* __restrict__ bg,
    unsigned short* __restrict__ theta, unsigned short* __restrict__ phi,
    unsigned short* __restrict__ gT, float* __restrict__ pzero)
{
    __shared__ unsigned short gst[32 * 20];   // [ci 32][m-local 16 +4]

    const int tid  = threadIdx.x;
    const int wid  = tid >> 6;
    const int lane = tid & 63;
    const int q = lane >> 4;
    const int c = lane & 15;

    // zero pacc+plsum (contiguous): 1,216,512 floats = 304,128 float4
    {
        const int gs = gridDim.x * blockDim.x;
        float4 z4 = {0.f, 0.f, 0.f, 0.f};
        for (int i = blockIdx.x * blockDim.x + tid; i < 304128; i += gs)
            ((float4*)pzero)[i] = z4;
    }

    const int b     = blockIdx.x / 288;
    const int rem   = blockIdx.x % 288;
    const int n0blk = rem * 32;
    const int n0    = n0blk + wid * 16;

    const float* Wm[3] = {wt, wp, wg};
    const float* Bm[3] = {bt, bp, bg};

    bf16x8 wf[3][2][2];
    float bias[3][2];
#pragma unroll
    for (int p = 0; p < 3; ++p) {
#pragma unroll
        for (int ct = 0; ct < 2; ++ct) {
            bias[p][ct] = Bm[p][ct * 16 + c];
#pragma unroll
            for (int ks = 0; ks < 2; ++ks) {
                const float* wsrc = Wm[p] + (ct * 16 + c) * 64 + ks * 32 + q * 8;
                f32x4 w0 = *(const f32x4*)wsrc;
                f32x4 w1 = *(const f32x4*)(wsrc + 4);
                unsigned* wk = (unsigned*)&wf[p][ct][ks];
                wk[0] = pk2(w0[0], w0[1]); wk[1] = pk2(w0[2], w0[3]);
                wk[2] = pk2(w1[0], w1[1]); wk[3] = pk2(w1[2], w1[3]);
            }
        }
    }

    bf16x8 af[2];
#pragma unroll
    for (int ks = 0; ks < 2; ++ks) {
        unsigned* ap = (unsigned*)&af[ks];
#pragma unroll
        for (int j2 = 0; j2 < 4; ++j2) {
            float x0 = x[(b * 64 + ks * 32 + q * 8 + j2 * 2) * NQ + n0 + c];
            float x1 = x[(b * 64 + ks * 32 + q * 8 + j2 * 2 + 1) * NQ + n0 + c];
            ap[j2] = pk2(x0, x1);
        }
    }

#pragma unroll
    for (int p = 0; p < 3; ++p) {
#pragma unroll
        for (int ct = 0; ct < 2; ++ct) {
            f32x4 acc = {0.f, 0.f, 0.f, 0.f};
            acc = __builtin_amdgcn_mfma_f32_16x16x32_bf16(af[0], wf[p][ct][0], acc, 0, 0, 0);
            acc = __builtin_amdgcn_mfma_f32_16x16x32_bf16(af[1], wf[p][ct][1], acc, 0, 0, 0);
#pragma unroll
            for (int r = 0; r < 4; ++r) acc[r] += bias[p][ct];
            const int ci = ct * 16 + c;
            if (p == 0) {
                unsigned pv0 = pk2(acc[0] * LOG2E, acc[1] * LOG2E);
                unsigned pv1 = pk2(acc[2] * LOG2E, acc[3] * LOG2E);
                theta[(b * NQ + n0 + 4 * q + 0) * 32 + ci] = (unsigned short)pv0;
                theta[(b * NQ + n0 + 4 * q + 1) * 32 + ci] = (unsigned short)(pv0 >> 16);
                theta[(b * NQ + n0 + 4 * q + 2) * 32 + ci] = (unsigned short)pv1;
                theta[(b * NQ + n0 + 4 * q + 3) * 32 + ci] = (unsigned short)(pv1 >> 16);
            } else {
                unsigned pv = pk2(fmaxf(acc[0], acc[1]), fmaxf(acc[2], acc[3]));
                if (p == 1) {
                    const int m0 = (n0 >> 1) + 2 * q;
                    phi[(b * MM + m0) * 32 + ci]     = (unsigned short)pv;
                    phi[(b * MM + m0 + 1) * 32 + ci] = (unsigned short)(pv >> 16);
                } else {
                    // m-local = wid*8 + 2q + {0,1}
                    *(unsigned int*)(gst + ci * 20 + wid * 8 + 2 * q) = pv;
                }
            }
        }
    }

    __syncthreads();
    {   // coalesced gT store: 16 m x 32 ci
        const int ci = tid >> 2;
        const int m4 = (tid & 3) * 4;
        u16x4 v = *(const u16x4*)(gst + ci * 20 + m4);
        *(u16x4*)(gT + (b * 32 + ci) * MM + rem * 16 + m4) = v;
    }
}

// ---------------------------------------------------------------------------
// Kernel 2: split-K flash attention, S^T form, 64 q-rows/wave, 32-m tiles.
// Per tile: LOAD_KF | PV(prev) | LOAD_VF | S/exp/write. Single per-wave P
// buffer is WAR-safe (same-wave DS in-order; PV(i-1) precedes S(i)).
// lsum: per-lane scalar accumulation of exp values, shfl_xor reduce at end.
// P^T [n 64][m 32] bf16, 16B-chunk XOR swizzle s=(c>>1)&3 -> 2-way conflicts
// max (free). Grid: KS*288 blocks x 128 thr (2 waves). TPW tiles each.
// ---------------------------------------------------------------------------
__global__ __launch_bounds__(128, 5) void attn_kernel(
    const unsigned short* __restrict__ theta, const unsigned short* __restrict__ phi,
    const unsigned short* __restrict__ gT,
    float* __restrict__ pacc, float* __restrict__ plsum)
{
    __shared__ unsigned short pld[2][64 * 32];   // per-wave P^T [n 64][m 32], 4KB/wave

    const int tid  = threadIdx.x;
    const int w    = tid >> 6;
    const int lane = tid & 63;
    const int q  = lane >> 4;
    const int c  = lane & 15;
    const int sw = ((c >> 1) & 3) << 3;   // XOR swizzle on the m short-index (16B chunks)

    const int ks  = blockIdx.x / 288;            // 0..KS-1
    const int rem = blockIdx.x % 288;
    const int b   = rem / 72;
    const int nb  = (rem % 72) * 128 + w * 64;   // this wave's first Q row

    // Q B-frags: theta[n][ch], lane col n = c (per rt tile), k = q*8+j
    bf16x8 qf[4];
#pragma unroll
    for (int rt = 0; rt < 4; ++rt)
        qf[rt] = *(const bf16x8*)(theta + (b * NQ + nb + rt * 16 + c) * 32 + q * 8);

    const unsigned short* phiB = phi + (size_t)b * MM * 32;
    const unsigned short* gTB  = gT + (size_t)b * 32 * MM;
    unsigned short* myp = pld[w];

    f32x4 acc[4][2];    // [rt n-tile][s2 ci-tile]: col=n, row=ci
    float lsum[4];      // per-lane partial sum of exp values (cols rt*16+c)
#pragma unroll
    for (int rt = 0; rt < 4; ++rt) {
        lsum[rt] = 0.f;
#pragma unroll
        for (int s2 = 0; s2 < 2; ++s2) acc[rt][s2] = (f32x4){0.f, 0.f, 0.f, 0.f};
    }

    const int t0 = ks * TPW;
    bf16x8 kf[2], vf[2];

#define LOAD_KF(m0) do {                                                      \
    kf[0] = *(const bf16x8*)(phiB + ((m0) + c) * 32 + q * 8);                 \
    kf[1] = *(const bf16x8*)(phiB + ((m0) + 16 + c) * 32 + q * 8);            \
} while (0)

#define LOAD_VF(m0) do {                                                      \
    vf[0] = *(const bf16x8*)(gTB + c * MM + (m0) + q * 8);                    \
    vf[1] = *(const bf16x8*)(gTB + (16 + c) * MM + (m0) + q * 8);             \
} while (0)

// S(rt): 2 S-MFMAs + 8 exp2 + lsum adds + 4 cvt_pk + 2 ds_write_b64
#define S_STEP(rt) do {                                                      \
    _Pragma("unroll")                                                        \
    for (int mct = 0; mct < 2; ++mct) {                                      \
        f32x4 z = {0.f, 0.f, 0.f, 0.f};                                      \
        f32x4 s = __builtin_amdgcn_mfma_f32_16x16x32_bf16(kf[mct], qf[rt], z, 0, 0, 0); \
        float e0 = __builtin_amdgcn_exp2f(s[0]);                             \
        float e1 = __builtin_amdgcn_exp2f(s[1]);                             \
        float e2 = __builtin_amdgcn_exp2f(s[2]);                             \
        float e3 = __builtin_amdgcn_exp2f(s[3]);                             \
        lsum[rt] += (e0 + e1) + (e2 + e3);                                   \
        uint2 hv = {pk2(e0, e1), pk2(e2, e3)};                               \
        *(uint2*)(myp + (((rt) * 16 + c) << 5) + ((mct * 16 + 4 * q) ^ sw)) = hv; \
    }                                                                        \
} while (0)

// PV(rt): 1 ds_read_b128 (full 32-m row) + 2 MFMAs
#define PV_STEP(rt) do {                                                     \
    bf16x8 pf = *(const bf16x8*)(myp + (((rt) * 16 + c) << 5) + ((q * 8) ^ sw)); \
    acc[rt][0] = __builtin_amdgcn_mfma_f32_16x16x32_bf16(vf[0], pf, acc[rt][0], 0, 0, 0); \
    acc[rt][1] = __builtin_amdgcn_mfma_f32_16x16x32_bf16(vf[1], pf, acc[rt][1], 0, 0, 0); \
} while (0)

    // ---- prologue: tile 0 S/exp/write ----
    LOAD_KF(t0 * 32);
    LOAD_VF(t0 * 32);
    S_STEP(0); S_STEP(1); S_STEP(2); S_STEP(3);

    // ---- steady state ----
    for (int mi = 1; mi < TPW; ++mi) {
        const int m0 = (t0 + mi) * 32;
        LOAD_KF(m0);                          // kf(i), consumed by S(i) below
        PV_STEP(0); PV_STEP(1); PV_STEP(2); PV_STEP(3);   // P(i-1) x vf(i-1)
        LOAD_VF(m0);                          // vf(i), consumed next iter
        S_STEP(0); S_STEP(1); S_STEP(2); S_STEP(3);
    }

    // ---- epilogue: PV of last tile ----
    PV_STEP(0); PV_STEP(1); PV_STEP(2); PV_STEP(3);

#undef LOAD_KF
#undef LOAD_VF
#undef S_STEP
#undef PV_STEP

    // accumulate partials: pacc[b][ci][n], 16-lane-contiguous per quad row
#pragma unroll
    for (int rt = 0; rt < 4; ++rt)
#pragma unroll
        for (int s2 = 0; s2 < 2; ++s2)
#pragma unroll
            for (int r = 0; r < 4; ++r)
                atomicAdd(&pacc[(size_t)(b * 32 + s2 * 16 + 4 * q + r) * NQ + nb + rt * 16 + c],
                          acc[rt][s2][r]);

    // lsum: butterfly across the 4 q-groups (lanes c, 16+c, 32+c, 48+c)
    float lv[4];
#pragma unroll
    for (int rt = 0; rt < 4; ++rt) {
        float v = lsum[rt];
        v += __shfl_xor(v, 16);
        v += __shfl_xor(v, 32);
        lv[rt] = v;
    }
    if (lane < 16) {
#pragma unroll
        for (int rt = 0; rt < 4; ++rt)
            atomicAdd(&plsum[(size_t)b * NQ + nb + rt * 16 + lane], lv[rt]);
    }
}

// ---------------------------------------------------------------------------
// Kernel 3: y^T = pacc/plsum -> LDS [ci][n] -> out = w_out.y^T + b + x.
// Grid: 1152 blocks x 128 thr (2 waves x 16 n), 32-n tiles.
// ---------------------------------------------------------------------------
__global__ __launch_bounds__(128, 4) void reduce_kernel(
    const float* __restrict__ pacc, const float* __restrict__ plsum,
    const float* __restrict__ w_out, const float* __restrict__ b_out,
    const float* __restrict__ x, float* __restrict__ out)
{
    __shared__ unsigned short yld[32 * 36];   // y^T tile: [ci 32][n 32+4]

    const int tid = threadIdx.x;
    const int b   = blockIdx.x / 288;
    const int nb  = (blockIdx.x % 288) * 32;

    // phase 1: coalesced read of pacc/plsum, divide, bf16, stage to LDS
    {
        const int ci = tid >> 2;
        const int n8 = (tid & 3) * 8;
        const float* pr = pacc + (size_t)(b * 32 + ci) * NQ + nb + n8;
        f32x4 a0 = *(const f32x4*)pr;
        f32x4 a1 = *(const f32x4*)(pr + 4);
        const float* lr = plsum + (size_t)b * NQ + nb + n8;
        f32x4 l0 = *(const f32x4*)lr;
        f32x4 l1 = *(const f32x4*)(lr + 4);
        uint2 v0 = {pk2(a0[0] / l0[0], a0[1] / l0[1]), pk2(a0[2] / l0[2], a0[3] / l0[3])};
        uint2 v1 = {pk2(a1[0] / l1[0], a1[1] / l1[1]), pk2(a1[2] / l1[2], a1[3] / l1[3])};
        *(uint2*)(yld + ci * 36 + n8)     = v0;
        *(uint2*)(yld + ci * 36 + n8 + 4) = v1;
    }
    __syncthreads();

    // phase 2: out-projection MFMA. A=w_out (rows chn, k=ci), B=y^T.
    const int w    = tid >> 6;
    const int lane = tid & 63;
    const int q = lane >> 4;
    const int c = lane & 15;

    bf16x8 wof[4];
#pragma unroll
    for (int ct = 0; ct < 4; ++ct) {
        const float* wsrc = w_out + (ct * 16 + c) * 32 + q * 8;
        f32x4 w0 = *(const f32x4*)wsrc;
        f32x4 w1 = *(const f32x4*)(wsrc + 4);
        unsigned* wk = (unsigned*)&wof[ct];
        wk[0] = pk2(w0[0], w0[1]); wk[1] = pk2(w0[2], w0[3]);
        wk[2] = pk2(w1[0], w1[1]); wk[3] = pk2(w1[2], w1[3]);
    }

    // B-frag: B[k=ci=q*8+j][col n=w*16+c] from yld[ci][n]
    bf16x8 yf;
    {
        unsigned short* yp = (unsigned short*)&yf;
#pragma unroll
        for (int j = 0; j < 8; ++j)
            yp[j] = yld[(q * 8 + j) * 36 + w * 16 + c];
    }

#pragma unroll
    for (int ct = 0; ct < 4; ++ct) {
        f32x4 z = {0.f, 0.f, 0.f, 0.f};
        f32x4 o = __builtin_amdgcn_mfma_f32_16x16x32_bf16(wof[ct], yf, z, 0, 0, 0);
#pragma unroll
        for (int r = 0; r < 4; ++r) {
            const int chn = ct * 16 + 4 * q + r;
            const size_t addr = (size_t)(b * 64 + chn) * NQ + nb + w * 16 + c;
            out[addr] = o[r] + b_out[chn] + x[addr];
        }
    }
}

extern "C" void kernel_launch(void* const* d_in, const int* in_sizes, int n_in,
                              void* d_out, int out_size, void* d_ws, size_t ws_size,
                              hipStream_t stream) {
    const float* x       = (const float*)d_in[0];
    const float* w_theta = (const float*)d_in[1];
    const float* b_theta = (const float*)d_in[2];
    const float* w_phi   = (const float*)d_in[3];
    const float* b_phi   = (const float*)d_in[4];
    const float* w_g     = (const float*)d_in[5];
    const float* b_g     = (const float*)d_in[6];
    const float* w_out   = (const float*)d_in[7];
    const float* b_out   = (const float*)d_in[8];
    float* out = (float*)d_out;

    // ws layout (bytes):
    //   theta bf16 [4][9216][32] : 2,359,296
    //   phi   bf16 [4][4608][32] : 1,179,648
    //   gT    bf16 [4][32][4608] : 1,179,648
    //   pacc  f32  [4][32][9216] : 4,718,592   (atomic accumulators)
    //   plsum f32  [4][9216]     :   147,456   (contiguous with pacc)
    unsigned short* theta = (unsigned short*)d_ws;
    unsigned short* phi   = theta + 4 * NQ * 32;
    unsigned short* gT    = phi + 4 * MM * 32;
    float* pacc  = (float*)(gT + 4 * 32 * MM);
    float* plsum = pacc + (size_t)4 * 32 * NQ;

    proj_kernel<<<1152, 128, 0, stream>>>(x, w_theta, b_theta, w_phi, b_phi,
                                          w_g, b_g, theta, phi, gT, pacc);
    attn_kernel<<<KS * 288, 128, 0, stream>>>(theta, phi, gT, pacc, plsum);
    reduce_kernel<<<1152, 128, 0, stream>>>(pacc, plsum, w_out, b_out, x, out);
}

// Round 3
// 149.028 us; speedup vs baseline: 1.1757x; 1.1757x over previous
//
#include <hip/hip_runtime.h>
#include <hip/hip_bf16.h>

// NonlocalBlock: B=4, C=64, H=W=96 (N=9216), Ci=32, COMPRESSION=2 (M=4608).
// R8: kill the global atomics. R5-R7 post-mortem: runtime = atomics/160G/s in
//     every round (9.4M/56us, 9.4M/59.6us, 14.2M/91us) -> attn was atomicAdd-
//     throughput-bound, not schedule- or occupancy-bound. New structure:
//     block = 4 waves m-splitting M=4608 (1152 m each) for one 64-q-row tile;
//     per-wave f32 partials meet in LDS (red/lred), get summed + normalized,
//     and y is written ONCE as bf16 [b][ci][n]. No pacc/plsum, no zero-fill,
//     reduce kernel becomes pure out-projection. Grid: 576 blocks x 256 thr.

#define NQ 9216
#define MM 4608
#define WM 1152        // m-range per wave (MM/4)
#define TPW 36         // 32-m tiles per wave
#define LOG2E 1.44269504088896340736f

typedef __attribute__((ext_vector_type(8))) short bf16x8;   // 8 bf16, 4 VGPRs
typedef __attribute__((ext_vector_type(4))) float f32x4;    // MFMA C/D
typedef __attribute__((ext_vector_type(4))) unsigned short u16x4;

static __device__ __forceinline__ unsigned pk2(float a, float b) {
    __hip_bfloat162 h = __float22bfloat162_rn(make_float2(a, b));
    return *reinterpret_cast<unsigned*>(&h);   // low16=a, high16=b
}

// ---------------------------------------------------------------------------
// Kernel 1: projections. 1152 blocks x 128 thr (2 waves, 1 n-tile of 16 each).
// theta pre-scaled by LOG2E; phi [m][ci]; gT [ci][m] via LDS transpose.
// (R8: zero-fill removed - no partial buffers anymore.)
// ---------------------------------------------------------------------------
__global__ __launch_bounds__(128, 4) void proj_kernel(
    const float* __restrict__ x,
    const float* __restrict__ wt, const float* __restrict__ bt,
    const float* __restrict__ wp, const float* __restrict__ bp,
    const float* __restrict__ wg, const float* __restrict__ bg,
    unsigned short* __restrict__ theta, unsigned short* __restrict__ phi,
    unsigned short* __restrict__ gT)
{
    __shared__ unsigned short gst[32 * 20];   // [ci 32][m-local 16 +4]

    const int tid  = threadIdx.x;
    const int wid  = tid >> 6;
    const int lane = tid & 63;
    const int q = lane >> 4;
    const int c = lane & 15;

    const int b     = blockIdx.x / 288;
    const int rem   = blockIdx.x % 288;
    const int n0    = rem * 32 + wid * 16;

    const float* Wm[3] = {wt, wp, wg};
    const float* Bm[3] = {bt, bp, bg};

    bf16x8 wf[3][2][2];
    float bias[3][2];
#pragma unroll
    for (int p = 0; p < 3; ++p) {
#pragma unroll
        for (int ct = 0; ct < 2; ++ct) {
            bias[p][ct] = Bm[p][ct * 16 + c];
#pragma unroll
            for (int ks = 0; ks < 2; ++ks) {
                const float* wsrc = Wm[p] + (ct * 16 + c) * 64 + ks * 32 + q * 8;
                f32x4 w0 = *(const f32x4*)wsrc;
                f32x4 w1 = *(const f32x4*)(wsrc + 4);
                unsigned* wk = (unsigned*)&wf[p][ct][ks];
                wk[0] = pk2(w0[0], w0[1]); wk[1] = pk2(w0[2], w0[3]);
                wk[2] = pk2(w1[0], w1[1]); wk[3] = pk2(w1[2], w1[3]);
            }
        }
    }

    bf16x8 af[2];
#pragma unroll
    for (int ks = 0; ks < 2; ++ks) {
        unsigned* ap = (unsigned*)&af[ks];
#pragma unroll
        for (int j2 = 0; j2 < 4; ++j2) {
            float x0 = x[(b * 64 + ks * 32 + q * 8 + j2 * 2) * NQ + n0 + c];
            float x1 = x[(b * 64 + ks * 32 + q * 8 + j2 * 2 + 1) * NQ + n0 + c];
            ap[j2] = pk2(x0, x1);
        }
    }

#pragma unroll
    for (int p = 0; p < 3; ++p) {
#pragma unroll
        for (int ct = 0; ct < 2; ++ct) {
            f32x4 acc = {0.f, 0.f, 0.f, 0.f};
            acc = __builtin_amdgcn_mfma_f32_16x16x32_bf16(af[0], wf[p][ct][0], acc, 0, 0, 0);
            acc = __builtin_amdgcn_mfma_f32_16x16x32_bf16(af[1], wf[p][ct][1], acc, 0, 0, 0);
#pragma unroll
            for (int r = 0; r < 4; ++r) acc[r] += bias[p][ct];
            const int ci = ct * 16 + c;
            if (p == 0) {
                unsigned pv0 = pk2(acc[0] * LOG2E, acc[1] * LOG2E);
                unsigned pv1 = pk2(acc[2] * LOG2E, acc[3] * LOG2E);
                theta[(b * NQ + n0 + 4 * q + 0) * 32 + ci] = (unsigned short)pv0;
                theta[(b * NQ + n0 + 4 * q + 1) * 32 + ci] = (unsigned short)(pv0 >> 16);
                theta[(b * NQ + n0 + 4 * q + 2) * 32 + ci] = (unsigned short)pv1;
                theta[(b * NQ + n0 + 4 * q + 3) * 32 + ci] = (unsigned short)(pv1 >> 16);
            } else {
                unsigned pv = pk2(fmaxf(acc[0], acc[1]), fmaxf(acc[2], acc[3]));
                if (p == 1) {
                    const int m0 = (n0 >> 1) + 2 * q;
                    phi[(b * MM + m0) * 32 + ci]     = (unsigned short)pv;
                    phi[(b * MM + m0 + 1) * 32 + ci] = (unsigned short)(pv >> 16);
                } else {
                    // m-local = wid*8 + 2q + {0,1}
                    *(unsigned int*)(gst + ci * 20 + wid * 8 + 2 * q) = pv;
                }
            }
        }
    }

    __syncthreads();
    {   // coalesced gT store: 16 m x 32 ci
        const int ci = tid >> 2;
        const int m4 = (tid & 3) * 4;
        u16x4 v = *(const u16x4*)(gst + ci * 20 + m4);
        *(u16x4*)(gT + (b * 32 + ci) * MM + rem * 16 + m4) = v;
    }
}

// ---------------------------------------------------------------------------
// Kernel 2: full-K attention, block = 4 waves m-splitting MM for one 64-q
// tile. Per wave: S^T flash loop over its 36 32-m tiles (same inner loop as
// R7, proven WAR-safe). Block epilogue: per-wave acc f32 -> LDS red[w][n][ci],
// lsum -> lred[w][n]; barrier; 256 threads sum the 4 slices, normalize, write
// y bf16 [b][ci][n] once. No atomics, no global partials.
// Grid: 576 blocks x 256 thr.
// ---------------------------------------------------------------------------
__global__ __launch_bounds__(256, 2) void attn_kernel(
    const unsigned short* __restrict__ theta, const unsigned short* __restrict__ phi,
    const unsigned short* __restrict__ gT,
    unsigned short* __restrict__ y)
{
    __shared__ unsigned short pld[4][64 * 32];   // per-wave P^T [n 64][m 32], 4KB each
    __shared__ float red[4][64][36];             // per-wave acc [n][ci 32 +4pad], 36KB
    __shared__ float lred[4][64];                // per-wave lsum per n, 1KB

    const int tid  = threadIdx.x;
    const int w    = tid >> 6;
    const int lane = tid & 63;
    const int q  = lane >> 4;
    const int c  = lane & 15;
    const int sw = ((c >> 1) & 3) << 3;   // XOR swizzle on the m short-index (16B chunks)

    const int b  = blockIdx.x / 144;
    const int nb = (blockIdx.x % 144) * 64;      // block's 64 q-rows (all 4 waves)

    // Q B-frags: theta[n][ch], lane col n = c (per rt tile), k = q*8+j
    bf16x8 qf[4];
#pragma unroll
    for (int rt = 0; rt < 4; ++rt)
        qf[rt] = *(const bf16x8*)(theta + (b * NQ + nb + rt * 16 + c) * 32 + q * 8);

    const unsigned short* phiB = phi + (size_t)b * MM * 32;
    const unsigned short* gTB  = gT + (size_t)b * 32 * MM;
    unsigned short* myp = pld[w];

    f32x4 acc[4][2];    // [rt n-tile][s2 ci-tile]: col=n, row=ci
    float lsum[4];      // per-lane partial sum of exp values (col n = rt*16+c)
#pragma unroll
    for (int rt = 0; rt < 4; ++rt) {
        lsum[rt] = 0.f;
#pragma unroll
        for (int s2 = 0; s2 < 2; ++s2) acc[rt][s2] = (f32x4){0.f, 0.f, 0.f, 0.f};
    }

    const int t0 = w * TPW;    // this wave's first 32-m tile
    bf16x8 kf[2], vf[2];

#define LOAD_KF(m0) do {                                                      \
    kf[0] = *(const bf16x8*)(phiB + ((m0) + c) * 32 + q * 8);                 \
    kf[1] = *(const bf16x8*)(phiB + ((m0) + 16 + c) * 32 + q * 8);            \
} while (0)

#define LOAD_VF(m0) do {                                                      \
    vf[0] = *(const bf16x8*)(gTB + c * MM + (m0) + q * 8);                    \
    vf[1] = *(const bf16x8*)(gTB + (16 + c) * MM + (m0) + q * 8);             \
} while (0)

// S(rt): 2 S-MFMAs + 8 exp2 + lsum adds + 4 cvt_pk + 2 ds_write_b64
#define S_STEP(rt) do {                                                      \
    _Pragma("unroll")                                                        \
    for (int mct = 0; mct < 2; ++mct) {                                      \
        f32x4 z = {0.f, 0.f, 0.f, 0.f};                                      \
        f32x4 s = __builtin_amdgcn_mfma_f32_16x16x32_bf16(kf[mct], qf[rt], z, 0, 0, 0); \
        float e0 = __builtin_amdgcn_exp2f(s[0]);                             \
        float e1 = __builtin_amdgcn_exp2f(s[1]);                             \
        float e2 = __builtin_amdgcn_exp2f(s[2]);                             \
        float e3 = __builtin_amdgcn_exp2f(s[3]);                             \
        lsum[rt] += (e0 + e1) + (e2 + e3);                                   \
        uint2 hv = {pk2(e0, e1), pk2(e2, e3)};                               \
        *(uint2*)(myp + (((rt) * 16 + c) << 5) + ((mct * 16 + 4 * q) ^ sw)) = hv; \
    }                                                                        \
} while (0)

// PV(rt): 1 ds_read_b128 (full 32-m row) + 2 MFMAs
#define PV_STEP(rt) do {                                                     \
    bf16x8 pf = *(const bf16x8*)(myp + (((rt) * 16 + c) << 5) + ((q * 8) ^ sw)); \
    acc[rt][0] = __builtin_amdgcn_mfma_f32_16x16x32_bf16(vf[0], pf, acc[rt][0], 0, 0, 0); \
    acc[rt][1] = __builtin_amdgcn_mfma_f32_16x16x32_bf16(vf[1], pf, acc[rt][1], 0, 0, 0); \
} while (0)

    // ---- prologue: tile 0 S/exp/write ----
    LOAD_KF(t0 * 32);
    LOAD_VF(t0 * 32);
    S_STEP(0); S_STEP(1); S_STEP(2); S_STEP(3);

    // ---- steady state ----
    for (int mi = 1; mi < TPW; ++mi) {
        const int m0 = (t0 + mi) * 32;
        LOAD_KF(m0);                          // kf(i), consumed by S(i) below
        PV_STEP(0); PV_STEP(1); PV_STEP(2); PV_STEP(3);   // P(i-1) x vf(i-1)
        LOAD_VF(m0);                          // vf(i), consumed next iter
        S_STEP(0); S_STEP(1); S_STEP(2); S_STEP(3);
    }

    // ---- epilogue: PV of last tile ----
    PV_STEP(0); PV_STEP(1); PV_STEP(2); PV_STEP(3);

#undef LOAD_KF
#undef LOAD_VF
#undef S_STEP
#undef PV_STEP

    // ---- stage per-wave partials to LDS ----
    // lsum: butterfly across the 4 q-groups -> total per col n for this m-range
#pragma unroll
    for (int rt = 0; rt < 4; ++rt) {
        float v = lsum[rt];
        v += __shfl_xor(v, 16);
        v += __shfl_xor(v, 32);
        if (lane < 16) lred[w][rt * 16 + lane] = v;
    }
    // acc: red[w][n = rt*16+c][ci base s2*16+4q], ds_write_b128 (16B aligned)
#pragma unroll
    for (int rt = 0; rt < 4; ++rt)
#pragma unroll
        for (int s2 = 0; s2 < 2; ++s2)
            *(f32x4*)&red[w][rt * 16 + c][s2 * 16 + 4 * q] = acc[rt][s2];

    __syncthreads();

    // ---- cross-wave sum + normalize + single bf16 y write ----
    {
        const int n   = tid & 63;
        const int cig = (tid >> 6) * 8;      // 8 ci values per thread
        float ls = (lred[0][n] + lred[1][n]) + (lred[2][n] + lred[3][n]);
        float inv = 1.0f / ls;
        f32x4 s0 = {0.f, 0.f, 0.f, 0.f}, s1 = {0.f, 0.f, 0.f, 0.f};
#pragma unroll
        for (int ww = 0; ww < 4; ++ww) {
            s0 += *(const f32x4*)&red[ww][n][cig];
            s1 += *(const f32x4*)&red[ww][n][cig + 4];
        }
        unsigned short* yb = y + (size_t)(b * 32 + cig) * NQ + nb + n;
#pragma unroll
        for (int k = 0; k < 4; ++k) {
            yb[(size_t)k * NQ]       = (unsigned short)(pk2(s0[k] * inv, 0.f) & 0xffff);
            yb[(size_t)(k + 4) * NQ] = (unsigned short)(pk2(s1[k] * inv, 0.f) & 0xffff);
        }
    }
}

// ---------------------------------------------------------------------------
// Kernel 3: out-projection. y bf16 [b][ci][n] -> LDS [ci][n] ->
// out = w_out.y^T + b + x. Grid: 1152 blocks x 128 thr (2 waves x 16 n).
// ---------------------------------------------------------------------------
__global__ __launch_bounds__(128, 4) void oproj_kernel(
    const unsigned short* __restrict__ y,
    const float* __restrict__ w_out, const float* __restrict__ b_out,
    const float* __restrict__ x, float* __restrict__ out)
{
    __shared__ unsigned short yld[32 * 36];   // y^T tile: [ci 32][n 32+4]

    const int tid = threadIdx.x;
    const int b   = blockIdx.x / 288;
    const int nb  = (blockIdx.x % 288) * 32;

    // phase 1: coalesced bf16 y tile load -> LDS
    {
        const int ci = tid >> 2;
        const int n8 = (tid & 3) * 8;
        const unsigned short* yr = y + (size_t)(b * 32 + ci) * NQ + nb + n8;
        uint2 v0 = *(const uint2*)yr;
        uint2 v1 = *(const uint2*)(yr + 4);
        *(uint2*)(yld + ci * 36 + n8)     = v0;
        *(uint2*)(yld + ci * 36 + n8 + 4) = v1;
    }
    __syncthreads();

    // phase 2: out-projection MFMA. A=w_out (rows chn, k=ci), B=y^T.
    const int w    = tid >> 6;
    const int lane = tid & 63;
    const int q = lane >> 4;
    const int c = lane & 15;

    bf16x8 wof[4];
#pragma unroll
    for (int ct = 0; ct < 4; ++ct) {
        const float* wsrc = w_out + (ct * 16 + c) * 32 + q * 8;
        f32x4 w0 = *(const f32x4*)wsrc;
        f32x4 w1 = *(const f32x4*)(wsrc + 4);
        unsigned* wk = (unsigned*)&wof[ct];
        wk[0] = pk2(w0[0], w0[1]); wk[1] = pk2(w0[2], w0[3]);
        wk[2] = pk2(w1[0], w1[1]); wk[3] = pk2(w1[2], w1[3]);
    }

    // B-frag: B[k=ci=q*8+j][col n=w*16+c] from yld[ci][n]
    bf16x8 yf;
    {
        unsigned short* yp = (unsigned short*)&yf;
#pragma unroll
        for (int j = 0; j < 8; ++j)
            yp[j] = yld[(q * 8 + j) * 36 + w * 16 + c];
    }

#pragma unroll
    for (int ct = 0; ct < 4; ++ct) {
        f32x4 z = {0.f, 0.f, 0.f, 0.f};
        f32x4 o = __builtin_amdgcn_mfma_f32_16x16x32_bf16(wof[ct], yf, z, 0, 0, 0);
#pragma unroll
        for (int r = 0; r < 4; ++r) {
            const int chn = ct * 16 + 4 * q + r;
            const size_t addr = (size_t)(b * 64 + chn) * NQ + nb + w * 16 + c;
            out[addr] = o[r] + b_out[chn] + x[addr];
        }
    }
}

extern "C" void kernel_launch(void* const* d_in, const int* in_sizes, int n_in,
                              void* d_out, int out_size, void* d_ws, size_t ws_size,
                              hipStream_t stream) {
    const float* x       = (const float*)d_in[0];
    const float* w_theta = (const float*)d_in[1];
    const float* b_theta = (const float*)d_in[2];
    const float* w_phi   = (const float*)d_in[3];
    const float* b_phi   = (const float*)d_in[4];
    const float* w_g     = (const float*)d_in[5];
    const float* b_g     = (const float*)d_in[6];
    const float* w_out   = (const float*)d_in[7];
    const float* b_out   = (const float*)d_in[8];
    float* out = (float*)d_out;

    // ws layout (bytes):
    //   theta bf16 [4][9216][32] : 2,359,296
    //   phi   bf16 [4][4608][32] : 1,179,648
    //   gT    bf16 [4][32][4608] : 1,179,648
    //   y     bf16 [4][32][9216] : 2,359,296
    unsigned short* theta = (unsigned short*)d_ws;
    unsigned short* phi   = theta + 4 * NQ * 32;
    unsigned short* gT    = phi + 4 * MM * 32;
    unsigned short* y     = gT + 4 * 32 * MM;

    proj_kernel<<<1152, 128, 0, stream>>>(x, w_theta, b_theta, w_phi, b_phi,
                                          w_g, b_g, theta, phi, gT);
    attn_kernel<<<576, 256, 0, stream>>>(theta, phi, gT, y);
    oproj_kernel<<<1152, 128, 0, stream>>>(y, w_out, b_out, x, out);
}

// Round 4
// 132.309 us; speedup vs baseline: 1.3243x; 1.1264x over previous
//
#include <hip/hip_runtime.h>
#include <hip/hip_bf16.h>

// NonlocalBlock: B=4, C=64, H=W=96 (N=9216), Ci=32, COMPRESSION=2 (M=4608).
// R9: re-grain R8 for occupancy + balance. R8 post-mortem: atomics gone (good)
//     but 54KB LDS + 576-block grid -> 13.6% occupancy, 2.25 blocks/CU tail.
//     Now: q-tile 48 rows (rt=3), grid 768 = exactly 3 blocks/CU, LDS 40.5KB
//     (3 blocks fit), launch_bounds(256,4) caps VGPR at 128 (tally ~77).
//     Same inner loop (proven), same LDS-tree reduction, no atomics.

#define NQ 9216
#define MM 4608
#define TPW 36         // 32-m tiles per wave (MM / 4 waves / 32)
#define LOG2E 1.44269504088896340736f

typedef __attribute__((ext_vector_type(8))) short bf16x8;   // 8 bf16, 4 VGPRs
typedef __attribute__((ext_vector_type(4))) float f32x4;    // MFMA C/D
typedef __attribute__((ext_vector_type(4))) unsigned short u16x4;

static __device__ __forceinline__ unsigned pk2(float a, float b) {
    __hip_bfloat162 h = __float22bfloat162_rn(make_float2(a, b));
    return *reinterpret_cast<unsigned*>(&h);   // low16=a, high16=b
}

// ---------------------------------------------------------------------------
// Kernel 1: projections. 1152 blocks x 128 thr (2 waves, 1 n-tile of 16 each).
// theta pre-scaled by LOG2E; phi [m][ci]; gT [ci][m] via LDS transpose.
// ---------------------------------------------------------------------------
__global__ __launch_bounds__(128, 4) void proj_kernel(
    const float* __restrict__ x,
    const float* __restrict__ wt, const float* __restrict__ bt,
    const float* __restrict__ wp, const float* __restrict__ bp,
    const float* __restrict__ wg, const float* __restrict__ bg,
    unsigned short* __restrict__ theta, unsigned short* __restrict__ phi,
    unsigned short* __restrict__ gT)
{
    __shared__ unsigned short gst[32 * 20];   // [ci 32][m-local 16 +4]

    const int tid  = threadIdx.x;
    const int wid  = tid >> 6;
    const int lane = tid & 63;
    const int q = lane >> 4;
    const int c = lane & 15;

    const int b     = blockIdx.x / 288;
    const int rem   = blockIdx.x % 288;
    const int n0    = rem * 32 + wid * 16;

    const float* Wm[3] = {wt, wp, wg};
    const float* Bm[3] = {bt, bp, bg};

    bf16x8 wf[3][2][2];
    float bias[3][2];
#pragma unroll
    for (int p = 0; p < 3; ++p) {
#pragma unroll
        for (int ct = 0; ct < 2; ++ct) {
            bias[p][ct] = Bm[p][ct * 16 + c];
#pragma unroll
            for (int ks = 0; ks < 2; ++ks) {
                const float* wsrc = Wm[p] + (ct * 16 + c) * 64 + ks * 32 + q * 8;
                f32x4 w0 = *(const f32x4*)wsrc;
                f32x4 w1 = *(const f32x4*)(wsrc + 4);
                unsigned* wk = (unsigned*)&wf[p][ct][ks];
                wk[0] = pk2(w0[0], w0[1]); wk[1] = pk2(w0[2], w0[3]);
                wk[2] = pk2(w1[0], w1[1]); wk[3] = pk2(w1[2], w1[3]);
            }
        }
    }

    bf16x8 af[2];
#pragma unroll
    for (int ks = 0; ks < 2; ++ks) {
        unsigned* ap = (unsigned*)&af[ks];
#pragma unroll
        for (int j2 = 0; j2 < 4; ++j2) {
            float x0 = x[(b * 64 + ks * 32 + q * 8 + j2 * 2) * NQ + n0 + c];
            float x1 = x[(b * 64 + ks * 32 + q * 8 + j2 * 2 + 1) * NQ + n0 + c];
            ap[j2] = pk2(x0, x1);
        }
    }

#pragma unroll
    for (int p = 0; p < 3; ++p) {
#pragma unroll
        for (int ct = 0; ct < 2; ++ct) {
            f32x4 acc = {0.f, 0.f, 0.f, 0.f};
            acc = __builtin_amdgcn_mfma_f32_16x16x32_bf16(af[0], wf[p][ct][0], acc, 0, 0, 0);
            acc = __builtin_amdgcn_mfma_f32_16x16x32_bf16(af[1], wf[p][ct][1], acc, 0, 0, 0);
#pragma unroll
            for (int r = 0; r < 4; ++r) acc[r] += bias[p][ct];
            const int ci = ct * 16 + c;
            if (p == 0) {
                unsigned pv0 = pk2(acc[0] * LOG2E, acc[1] * LOG2E);
                unsigned pv1 = pk2(acc[2] * LOG2E, acc[3] * LOG2E);
                theta[(b * NQ + n0 + 4 * q + 0) * 32 + ci] = (unsigned short)pv0;
                theta[(b * NQ + n0 + 4 * q + 1) * 32 + ci] = (unsigned short)(pv0 >> 16);
                theta[(b * NQ + n0 + 4 * q + 2) * 32 + ci] = (unsigned short)pv1;
                theta[(b * NQ + n0 + 4 * q + 3) * 32 + ci] = (unsigned short)(pv1 >> 16);
            } else {
                unsigned pv = pk2(fmaxf(acc[0], acc[1]), fmaxf(acc[2], acc[3]));
                if (p == 1) {
                    const int m0 = (n0 >> 1) + 2 * q;
                    phi[(b * MM + m0) * 32 + ci]     = (unsigned short)pv;
                    phi[(b * MM + m0 + 1) * 32 + ci] = (unsigned short)(pv >> 16);
                } else {
                    // m-local = wid*8 + 2q + {0,1}
                    *(unsigned int*)(gst + ci * 20 + wid * 8 + 2 * q) = pv;
                }
            }
        }
    }

    __syncthreads();
    {   // coalesced gT store: 16 m x 32 ci
        const int ci = tid >> 2;
        const int m4 = (tid & 3) * 4;
        u16x4 v = *(const u16x4*)(gst + ci * 20 + m4);
        *(u16x4*)(gT + (b * 32 + ci) * MM + rem * 16 + m4) = v;
    }
}

// ---------------------------------------------------------------------------
// Kernel 2: full-K attention. Block = 4 waves m-splitting MM for one 48-q-row
// tile (rt=3). Per wave: S^T flash loop over 36 32-m tiles (R7/R8 inner loop,
// WAR-safe single P buffer). Epilogue: per-wave f32 partials -> LDS red/lred,
// barrier, 192 threads sum 4 slices, normalize, write y bf16 [b][ci][n] once.
// Grid: 768 blocks x 256 thr = exactly 3 blocks/CU (balanced makespan).
// ---------------------------------------------------------------------------
__global__ __launch_bounds__(256, 4) void attn_kernel(
    const unsigned short* __restrict__ theta, const unsigned short* __restrict__ phi,
    const unsigned short* __restrict__ gT,
    unsigned short* __restrict__ y)
{
    __shared__ unsigned short pld[4][48 * 32];   // per-wave P^T [n 48][m 32], 3KB each
    __shared__ float red[4][48][36];             // per-wave acc [n][ci 32 +4pad], 27.6KB
    __shared__ float lred[4][48];                // per-wave lsum per n

    const int tid  = threadIdx.x;
    const int w    = tid >> 6;
    const int lane = tid & 63;
    const int q  = lane >> 4;
    const int c  = lane & 15;
    const int sw = ((c >> 1) & 3) << 3;   // XOR swizzle on the m short-index (16B chunks)

    const int b  = blockIdx.x / 192;
    const int nb = (blockIdx.x % 192) * 48;      // block's 48 q-rows (all 4 waves)

    // Q B-frags: theta[n][ch], lane col n = c (per rt tile), k = q*8+j
    bf16x8 qf[3];
#pragma unroll
    for (int rt = 0; rt < 3; ++rt)
        qf[rt] = *(const bf16x8*)(theta + (b * NQ + nb + rt * 16 + c) * 32 + q * 8);

    const unsigned short* phiB = phi + (size_t)b * MM * 32;
    const unsigned short* gTB  = gT + (size_t)b * 32 * MM;
    unsigned short* myp = pld[w];

    f32x4 acc[3][2];    // [rt n-tile][s2 ci-tile]: col=n, row=ci
    float lsum[3];      // per-lane partial sum of exp values (col n = rt*16+c)
#pragma unroll
    for (int rt = 0; rt < 3; ++rt) {
        lsum[rt] = 0.f;
#pragma unroll
        for (int s2 = 0; s2 < 2; ++s2) acc[rt][s2] = (f32x4){0.f, 0.f, 0.f, 0.f};
    }

    const int t0 = w * TPW;    // this wave's first 32-m tile
    bf16x8 kf[2], vf[2];

#define LOAD_KF(m0) do {                                                      \
    kf[0] = *(const bf16x8*)(phiB + ((m0) + c) * 32 + q * 8);                 \
    kf[1] = *(const bf16x8*)(phiB + ((m0) + 16 + c) * 32 + q * 8);            \
} while (0)

#define LOAD_VF(m0) do {                                                      \
    vf[0] = *(const bf16x8*)(gTB + c * MM + (m0) + q * 8);                    \
    vf[1] = *(const bf16x8*)(gTB + (16 + c) * MM + (m0) + q * 8);             \
} while (0)

// S(rt): 2 S-MFMAs + 8 exp2 + lsum adds + 4 cvt_pk + 2 ds_write_b64
#define S_STEP(rt) do {                                                      \
    _Pragma("unroll")                                                        \
    for (int mct = 0; mct < 2; ++mct) {                                      \
        f32x4 z = {0.f, 0.f, 0.f, 0.f};                                      \
        f32x4 s = __builtin_amdgcn_mfma_f32_16x16x32_bf16(kf[mct], qf[rt], z, 0, 0, 0); \
        float e0 = __builtin_amdgcn_exp2f(s[0]);                             \
        float e1 = __builtin_amdgcn_exp2f(s[1]);                             \
        float e2 = __builtin_amdgcn_exp2f(s[2]);                             \
        float e3 = __builtin_amdgcn_exp2f(s[3]);                             \
        lsum[rt] += (e0 + e1) + (e2 + e3);                                   \
        uint2 hv = {pk2(e0, e1), pk2(e2, e3)};                               \
        *(uint2*)(myp + (((rt) * 16 + c) << 5) + ((mct * 16 + 4 * q) ^ sw)) = hv; \
    }                                                                        \
} while (0)

// PV(rt): 1 ds_read_b128 (full 32-m row) + 2 MFMAs
#define PV_STEP(rt) do {                                                     \
    bf16x8 pf = *(const bf16x8*)(myp + (((rt) * 16 + c) << 5) + ((q * 8) ^ sw)); \
    acc[rt][0] = __builtin_amdgcn_mfma_f32_16x16x32_bf16(vf[0], pf, acc[rt][0], 0, 0, 0); \
    acc[rt][1] = __builtin_amdgcn_mfma_f32_16x16x32_bf16(vf[1], pf, acc[rt][1], 0, 0, 0); \
} while (0)

    // ---- prologue: tile 0 S/exp/write ----
    LOAD_KF(t0 * 32);
    LOAD_VF(t0 * 32);
    S_STEP(0); S_STEP(1); S_STEP(2);

    // ---- steady state ----
    for (int mi = 1; mi < TPW; ++mi) {
        const int m0 = (t0 + mi) * 32;
        LOAD_KF(m0);                          // kf(i), consumed by S(i) below
        PV_STEP(0); PV_STEP(1); PV_STEP(2);   // P(i-1) x vf(i-1)
        LOAD_VF(m0);                          // vf(i), consumed next iter
        S_STEP(0); S_STEP(1); S_STEP(2);
    }

    // ---- epilogue: PV of last tile ----
    PV_STEP(0); PV_STEP(1); PV_STEP(2);

#undef LOAD_KF
#undef LOAD_VF
#undef S_STEP
#undef PV_STEP

    // ---- stage per-wave partials to LDS ----
    // lsum: butterfly across the 4 q-groups -> total per col n for this m-range
#pragma unroll
    for (int rt = 0; rt < 3; ++rt) {
        float v = lsum[rt];
        v += __shfl_xor(v, 16);
        v += __shfl_xor(v, 32);
        if (lane < 16) lred[w][rt * 16 + lane] = v;
    }
    // acc: red[w][n = rt*16+c][ci base s2*16+4q], ds_write_b128 (16B aligned)
#pragma unroll
    for (int rt = 0; rt < 3; ++rt)
#pragma unroll
        for (int s2 = 0; s2 < 2; ++s2)
            *(f32x4*)&red[w][rt * 16 + c][s2 * 16 + 4 * q] = acc[rt][s2];

    __syncthreads();

    // ---- cross-wave sum + normalize + single bf16 y write ----
    {
        const int n   = tid & 63;            // 0..63, active if < 48
        const int cig = (tid >> 6) * 8;      // 8 ci values per thread
        if (n < 48) {
            float ls = (lred[0][n] + lred[1][n]) + (lred[2][n] + lred[3][n]);
            float inv = 1.0f / ls;
            f32x4 s0 = {0.f, 0.f, 0.f, 0.f}, s1 = {0.f, 0.f, 0.f, 0.f};
#pragma unroll
            for (int ww = 0; ww < 4; ++ww) {
                s0 += *(const f32x4*)&red[ww][n][cig];
                s1 += *(const f32x4*)&red[ww][n][cig + 4];
            }
            unsigned short* yb = y + (size_t)(b * 32 + cig) * NQ + nb + n;
#pragma unroll
            for (int k = 0; k < 4; ++k) {
                yb[(size_t)k * NQ]       = (unsigned short)(pk2(s0[k] * inv, 0.f) & 0xffff);
                yb[(size_t)(k + 4) * NQ] = (unsigned short)(pk2(s1[k] * inv, 0.f) & 0xffff);
            }
        }
    }
}

// ---------------------------------------------------------------------------
// Kernel 3: out-projection. y bf16 [b][ci][n] -> LDS [ci][n] ->
// out = w_out.y^T + b + x. Grid: 1152 blocks x 128 thr (2 waves x 16 n).
// ---------------------------------------------------------------------------
__global__ __launch_bounds__(128, 4) void oproj_kernel(
    const unsigned short* __restrict__ y,
    const float* __restrict__ w_out, const float* __restrict__ b_out,
    const float* __restrict__ x, float* __restrict__ out)
{
    __shared__ unsigned short yld[32 * 36];   // y^T tile: [ci 32][n 32+4]

    const int tid = threadIdx.x;
    const int b   = blockIdx.x / 288;
    const int nb  = (blockIdx.x % 288) * 32;

    // phase 1: coalesced bf16 y tile load -> LDS
    {
        const int ci = tid >> 2;
        const int n8 = (tid & 3) * 8;
        const unsigned short* yr = y + (size_t)(b * 32 + ci) * NQ + nb + n8;
        uint2 v0 = *(const uint2*)yr;
        uint2 v1 = *(const uint2*)(yr + 4);
        *(uint2*)(yld + ci * 36 + n8)     = v0;
        *(uint2*)(yld + ci * 36 + n8 + 4) = v1;
    }
    __syncthreads();

    // phase 2: out-projection MFMA. A=w_out (rows chn, k=ci), B=y^T.
    const int w    = tid >> 6;
    const int lane = tid & 63;
    const int q = lane >> 4;
    const int c = lane & 15;

    bf16x8 wof[4];
#pragma unroll
    for (int ct = 0; ct < 4; ++ct) {
        const float* wsrc = w_out + (ct * 16 + c) * 32 + q * 8;
        f32x4 w0 = *(const f32x4*)wsrc;
        f32x4 w1 = *(const f32x4*)(wsrc + 4);
        unsigned* wk = (unsigned*)&wof[ct];
        wk[0] = pk2(w0[0], w0[1]); wk[1] = pk2(w0[2], w0[3]);
        wk[2] = pk2(w1[0], w1[1]); wk[3] = pk2(w1[2], w1[3]);
    }

    // B-frag: B[k=ci=q*8+j][col n=w*16+c] from yld[ci][n]
    bf16x8 yf;
    {
        unsigned short* yp = (unsigned short*)&yf;
#pragma unroll
        for (int j = 0; j < 8; ++j)
            yp[j] = yld[(q * 8 + j) * 36 + w * 16 + c];
    }

#pragma unroll
    for (int ct = 0; ct < 4; ++ct) {
        f32x4 z = {0.f, 0.f, 0.f, 0.f};
        f32x4 o = __builtin_amdgcn_mfma_f32_16x16x32_bf16(wof[ct], yf, z, 0, 0, 0);
#pragma unroll
        for (int r = 0; r < 4; ++r) {
            const int chn = ct * 16 + 4 * q + r;
            const size_t addr = (size_t)(b * 64 + chn) * NQ + nb + w * 16 + c;
            out[addr] = o[r] + b_out[chn] + x[addr];
        }
    }
}

extern "C" void kernel_launch(void* const* d_in, const int* in_sizes, int n_in,
                              void* d_out, int out_size, void* d_ws, size_t ws_size,
                              hipStream_t stream) {
    const float* x       = (const float*)d_in[0];
    const float* w_theta = (const float*)d_in[1];
    const float* b_theta = (const float*)d_in[2];
    const float* w_phi   = (const float*)d_in[3];
    const float* b_phi   = (const float*)d_in[4];
    const float* w_g     = (const float*)d_in[5];
    const float* b_g     = (const float*)d_in[6];
    const float* w_out   = (const float*)d_in[7];
    const float* b_out   = (const float*)d_in[8];
    float* out = (float*)d_out;

    // ws layout (bytes):
    //   theta bf16 [4][9216][32] : 2,359,296
    //   phi   bf16 [4][4608][32] : 1,179,648
    //   gT    bf16 [4][32][4608] : 1,179,648
    //   y     bf16 [4][32][9216] : 2,359,296
    unsigned short* theta = (unsigned short*)d_ws;
    unsigned short* phi   = theta + 4 * NQ * 32;
    unsigned short* gT    = phi + 4 * MM * 32;
    unsigned short* y     = gT + 4 * 32 * MM;

    proj_kernel<<<1152, 128, 0, stream>>>(x, w_theta, b_theta, w_phi, b_phi,
                                          w_g, b_g, theta, phi, gT);
    attn_kernel<<<768, 256, 0, stream>>>(theta, phi, gT, y);
    oproj_kernel<<<1152, 128, 0, stream>>>(y, w_out, b_out, x, out);
}